// Round 5
// baseline (222.450 us; speedup 1.0000x reference)
//
#include <hip/hip_runtime.h>
#include <hip/hip_fp16.h>
#include <math.h>

#ifndef M_PI
#define M_PI 3.14159265358979323846
#endif

#define HP   2080          // padded height (2048 + 2*16)
#define WP   2080          // padded width
#define MARG 16
#define HOUT 2048
#define WOUT 2048
#define RAD  26            // truncation radius; g[26]/g[0] ~ 4e-16
#define KW   53            // expanded symmetric kernel width
#define TSH  6
#define TS   64            // splat tile size
#define TP   65            // tile + halo
#define TDIM 33
#define NT   (TDIM * TDIM) // 1089 bins
#define HIST_BLOCKS 512
#define SCAT_BLOCKS 128

__device__ __forceinline__ int bin_of(float px, float py, int& row, int& col) {
    col = (int)floorf(px); row = (int)floorf(py);
    row = min(max(row, 0), HP - 1);
    col = min(max(col, 0), WP - 1);
    return (row >> TSH) * TDIM + (col >> TSH);
}

// --- fused: blocks <512 do per-bin histogram; blocks 512..538 compute filter taps
// g[n] = (1/N) sum_j exp(-f_j^2 * 200) cos(2*pi*j*n/N)  (exact discrete weights)
__global__ void hist_weights_kernel(const float2* __restrict__ pos,
                                    int* __restrict__ hist,
                                    float* __restrict__ w, int n) {
    __shared__ int lh[NT];
    __shared__ double partial[256];
    const int tid = threadIdx.x;
    if (blockIdx.x >= HIST_BLOCKS) {
        const int tap = blockIdx.x - HIST_BLOCKS;   // 0..26
        const double N = (double)WP;
        double s = 0.0;
        for (int j = tid; j < WP; j += 256) {
            double f = ((j <= WP / 2) ? (double)j : (double)(j - WP)) / N;
            s += exp(-(f * f) * 200.0) * cos(2.0 * M_PI * (double)j * (double)tap / N);
        }
        partial[tid] = s;
        __syncthreads();
        for (int off = 128; off > 0; off >>= 1) {
            if (tid < off) partial[tid] += partial[tid + off];
            __syncthreads();
        }
        if (tid == 0) w[tap] = (float)(partial[0] / N);
        return;
    }
    for (int i = tid; i < NT; i += 256) lh[i] = 0;
    __syncthreads();
    for (int i = blockIdx.x * 256 + tid; i < n; i += HIST_BLOCKS * 256) {
        float2 p = pos[i]; int r, c;
        atomicAdd(&lh[bin_of(p.x + MARG, p.y + MARG, r, c)], 1);
    }
    __syncthreads();
    for (int i = tid; i < NT; i += 256)
        if (lh[i]) atomicAdd(&hist[i], lh[i]);
}

// --- scatter: each block scans hist locally in LDS (no separate scan kernel),
// reserves per-bin runs (~7.2 recs = 57 B contiguous), writes 8-B packed records.
__global__ __launch_bounds__(1024) void scatter_kernel(const float2* __restrict__ pos,
                                                       const float* __restrict__ inten,
                                                       const int* __restrict__ hist,
                                                       int* __restrict__ cursorRel,
                                                       int* __restrict__ binStart,
                                                       ushort4* __restrict__ bins, int n) {
    __shared__ int sc[1024];
    __shared__ int bs[NT + 1];
    __shared__ int lhist[NT];
    __shared__ int lbase[NT];
    const int tid = threadIdx.x;
    int h0 = (2 * tid     < NT) ? hist[2 * tid]     : 0;
    int h1 = (2 * tid + 1 < NT) ? hist[2 * tid + 1] : 0;
    sc[tid] = h0 + h1;
    for (int i = tid; i < NT; i += 1024) lhist[i] = 0;
    __syncthreads();
    for (int off = 1; off < 1024; off <<= 1) {
        int v = sc[tid];
        if (tid >= off) v += sc[tid - off];
        __syncthreads();
        sc[tid] = v;
        __syncthreads();
    }
    int excl = sc[tid] - (h0 + h1);
    if (2 * tid     < NT) bs[2 * tid]     = excl;
    if (2 * tid + 1 < NT) bs[2 * tid + 1] = excl + h0;
    if (tid == 1023) bs[NT] = sc[1023];
    __syncthreads();

    const int stride = SCAT_BLOCKS * 1024;
    const int start  = blockIdx.x * 1024 + tid;
    for (int i = start; i < n; i += stride) {
        float2 p = pos[i]; int r, c;
        atomicAdd(&lhist[bin_of(p.x + MARG, p.y + MARG, r, c)], 1);
    }
    __syncthreads();
    for (int i = tid; i < NT; i += 1024) {
        int c = lhist[i];
        lbase[i] = (c > 0) ? (bs[i] + atomicAdd(&cursorRel[i], c)) : 0;
        lhist[i] = 0;
    }
    __syncthreads();
    for (int i = start; i < n; i += stride) {
        float2 p = pos[i];
        float px = p.x + MARG, py = p.y + MARG;
        int row, col;
        int bin = bin_of(px, py, row, col);
        float dy = py - (float)row, dx = px - (float)col;
        int off = atomicAdd(&lhist[bin], 1);
        ushort4 rec;
        rec.x = (unsigned short)(((row & 63) << 6) | (col & 63));
        rec.y = __half_as_ushort(__float2half(dx));
        rec.z = __half_as_ushort(__float2half(dy));
        rec.w = __half_as_ushort(__float2half(inten[i]));
        bins[lbase[bin] + off] = rec;
    }
    if (blockIdx.x == 0)
        for (int i = tid; i <= NT; i += 1024) binStart[i] = bs[i];
}

// --- per-tile splat via LDS atomics, then coalesced canvas write
__global__ __launch_bounds__(512, 8) void tile_splat_kernel(const ushort4* __restrict__ bins,
                                                            const int* __restrict__ binStart,
                                                            float* __restrict__ canvas) {
    __shared__ float tile[TP * TP];   // 16.9 KB
    const int b  = blockIdx.x;
    const int ti = b / TDIM, tj = b % TDIM;
    for (int i = threadIdx.x; i < TP * TP; i += 512) tile[i] = 0.0f;
    __syncthreads();
    const int s0 = binStart[b], s1 = binStart[b + 1];
    for (int i = s0 + threadIdx.x; i < s1; i += 512) {
        ushort4 r = bins[i];
        int cell = r.x;
        float dx = __half2float(__ushort_as_half(r.y));
        float dy = __half2float(__ushort_as_half(r.z));
        float I  = __half2float(__ushort_as_half(r.w));
        int lr = cell >> 6, lc = cell & 63;
        float omdy = 1.0f - dy, omdx = 1.0f - dx;
        atomicAdd(&tile[lr * TP + lc],           omdy * omdx * I);
        atomicAdd(&tile[(lr + 1) * TP + lc],     dy   * omdx * I);
        atomicAdd(&tile[lr * TP + lc + 1],       omdy * dx   * I);
        atomicAdd(&tile[(lr + 1) * TP + lc + 1], dy   * dx   * I);
    }
    __syncthreads();
    for (int i = threadIdx.x; i < TP * TP; i += 512) {
        int r = i / TP, c = i - r * TP;
        int gr = (ti << TSH) + r, gc = (tj << TSH) + c;
        if (gr < HP && gc < WP) {
            float v = tile[i];
            bool edge = (r == 0) | (c == 0) | (r == TS) | (c == TS);
            if (edge) { if (v != 0.0f) atomicAdd(&canvas[gr * WP + gc], v); }
            else canvas[gr * WP + gc] = v;
        }
    }
}

// --- horizontal conv, register-window, 4 outputs/thread, only x in [16,2064)
__global__ __launch_bounds__(256) void hconv_kernel(const float* __restrict__ canvas,
                                                    const float* __restrict__ w,
                                                    float* __restrict__ temp) {
    __shared__ float s[1024 + 52];
    __shared__ float wk[KW];
    const int tid = threadIdx.x;
    const int y   = blockIdx.y;
    const int x0  = MARG + (blockIdx.x << 10);    // 16 or 1040
    if (tid < KW) wk[tid] = w[abs(tid - RAD)];
    for (int i = tid; i < 1024 + 52; i += 256) {
        int x = x0 - RAD + i;
        s[i] = ((unsigned)x < WP) ? canvas[y * WP + x] : 0.0f;
    }
    __syncthreads();
    const int k4 = tid << 2;
    float win[56];
#pragma unroll
    for (int i = 0; i < 56; ++i) win[i] = s[k4 + i];
    float a0 = 0, a1 = 0, a2 = 0, a3 = 0;
#pragma unroll
    for (int u = 0; u < KW; ++u) {
        float c = wk[u];
        a0 += win[u] * c; a1 += win[u + 1] * c;
        a2 += win[u + 2] * c; a3 += win[u + 3] * c;
    }
    float4 o; o.x = a0; o.y = a1; o.z = a2; o.w = a3;
    *(float4*)&temp[y * WP + x0 + k4] = o;
}

// --- vertical conv + crop, register-window, 4 outputs/thread per group
__global__ __launch_bounds__(256) void vconv_kernel(const float* __restrict__ temp,
                                                    const float* __restrict__ w,
                                                    float* __restrict__ out) {
    __shared__ float s[TS + 52][64];   // 29.0 KB
    __shared__ float wk[KW];
    const int lx  = threadIdx.x;       // 0..63
    const int ly  = threadIdx.y;       // 0..3
    const int tid = ly * 64 + lx;
    if (tid < KW) wk[tid] = w[abs(tid - RAD)];
    const int ox0 = blockIdx.x << 6, oy0 = blockIdx.y << 6;
    const int cx  = ox0 + lx + MARG;
    for (int r = ly; r < TS + 52; r += 4) {
        int cy = oy0 + MARG - RAD + r;
        s[r][lx] = ((unsigned)cy < HP) ? temp[cy * WP + cx] : 0.0f;
    }
    __syncthreads();
    for (int g = 0; g < 4; ++g) {
        const int yy0 = (ly << 4) + (g << 2);
        float win[56];
#pragma unroll
        for (int i = 0; i < 56; ++i) win[i] = s[yy0 + i][lx];
        float a0 = 0, a1 = 0, a2 = 0, a3 = 0;
#pragma unroll
        for (int u = 0; u < KW; ++u) {
            float c = wk[u];
            a0 += win[u] * c; a1 += win[u + 1] * c;
            a2 += win[u + 2] * c; a3 += win[u + 3] * c;
        }
        out[(oy0 + yy0    ) * WOUT + ox0 + lx] = a0;
        out[(oy0 + yy0 + 1) * WOUT + ox0 + lx] = a1;
        out[(oy0 + yy0 + 2) * WOUT + ox0 + lx] = a2;
        out[(oy0 + yy0 + 3) * WOUT + ox0 + lx] = a3;
    }
}

extern "C" void kernel_launch(void* const* d_in, const int* in_sizes, int n_in,
                              void* d_out, int out_size, void* d_ws, size_t ws_size,
                              hipStream_t stream) {
    const float2* pos   = (const float2*)d_in[0];   // (N,2) as (x,y)
    const float*  inten = (const float*)d_in[1];
    const int n = in_sizes[1];

    float*   canvas   = (float*)d_ws;                       // HP*WP floats
    int*     hist     = (int*)(canvas + (size_t)HP * WP);   // NT
    int*     cursor   = hist + NT;                          // NT
    int*     binStart = cursor + NT;                        // NT+1
    float*   temp     = canvas + (size_t)HP * WP + 4096;    // HP*WP floats
    ushort4* bins     = (ushort4*)temp;                     // n * 8 B, aliases temp
    float*   w        = temp + (size_t)HP * WP;             // 27 floats

    // zero canvas + hist + cursor in one fill (binStart fully written by scatter)
    hipMemsetAsync(canvas, 0, ((size_t)HP * WP + 2 * NT) * sizeof(float), stream);
    hist_weights_kernel<<<HIST_BLOCKS + RAD + 1, 256, 0, stream>>>(pos, hist, w, n);
    scatter_kernel<<<SCAT_BLOCKS, 1024, 0, stream>>>(pos, inten, hist, cursor, binStart, bins, n);
    tile_splat_kernel<<<NT, 512, 0, stream>>>(bins, binStart, canvas);
    hconv_kernel<<<dim3(2, HP), 256, 0, stream>>>(canvas, w, temp);
    vconv_kernel<<<dim3(WOUT / 64, HOUT / 64), dim3(64, 4), 0, stream>>>(temp, w, (float*)d_out);
}

// Round 7
// 175.405 us; speedup vs baseline: 1.2682x; 1.2682x over previous
//
#include <hip/hip_runtime.h>
#include <hip/hip_fp16.h>
#include <math.h>

#define HP   2080          // padded height (2048 + 2*16)
#define WP   2080          // padded width
#define MARG 16
#define HOUT 2048
#define WOUT 2048
#define RAD  16            // truncation radius; tail mass ~2e-7 (threshold 9.9e-3)
#define TSH  6
#define TS   64            // splat tile size
#define TP   65            // tile + halo
#define TDIM 33
#define NT   (TDIM * TDIM) // 1089 bins
#define HIST_BLOCKS 256
#define SCAT_BLOCKS 256
#define SCAT_IT 4          // 256*1024*4 = 1,048,576 >= N

// exact discrete tap via Poisson summation: g[n] = sqrt(pi/200)*exp(-pi^2 n^2/200)
__device__ __forceinline__ void make_weights(float* wreg) {
#pragma unroll
    for (int t = 0; t <= RAD; ++t)
        wreg[t] = 0.12533141373155003f * __expf(-0.04934802200544679f * (float)(t * t));
}

__device__ __forceinline__ int bin_of(float px, float py, int& row, int& col) {
    col = (int)floorf(px); row = (int)floorf(py);
    row = min(max(row, 0), HP - 1);
    col = min(max(col, 0), WP - 1);
    return (row >> TSH) * TDIM + (col >> TSH);
}

// --- pass 1: per-bin histogram (LDS-aggregated)
__global__ void hist_kernel(const float2* __restrict__ pos, int* __restrict__ hist, int n) {
    __shared__ int lh[NT];
    const int tid = threadIdx.x;
    for (int i = tid; i < NT; i += 256) lh[i] = 0;
    __syncthreads();
    for (int i = blockIdx.x * 256 + tid; i < n; i += HIST_BLOCKS * 256) {
        float2 p = pos[i]; int r, c;
        atomicAdd(&lh[bin_of(p.x + MARG, p.y + MARG, r, c)], 1);
    }
    __syncthreads();
    for (int i = tid; i < NT; i += 256)
        if (lh[i]) atomicAdd(&hist[i], lh[i]);
}

// --- pass 2: scatter. Each block scans hist in LDS (no scan kernel); single read
// of pos/inten (records cached in registers between count and write passes).
__global__ __launch_bounds__(1024) void scatter_kernel(const float2* __restrict__ pos,
                                                       const float* __restrict__ inten,
                                                       const int* __restrict__ hist,
                                                       int* __restrict__ cursorRel,
                                                       int* __restrict__ binStart,
                                                       ushort4* __restrict__ bins, int n) {
    __shared__ int sc[1024];
    __shared__ int bs[NT + 1];
    __shared__ int lhist[NT];
    __shared__ int lbase[NT];
    const int tid = threadIdx.x;
    int h0 = (2 * tid     < NT) ? hist[2 * tid]     : 0;
    int h1 = (2 * tid + 1 < NT) ? hist[2 * tid + 1] : 0;
    sc[tid] = h0 + h1;
    for (int i = tid; i < NT; i += 1024) lhist[i] = 0;
    __syncthreads();
    for (int off = 1; off < 1024; off <<= 1) {
        int v = sc[tid];
        if (tid >= off) v += sc[tid - off];
        __syncthreads();
        sc[tid] = v;
        __syncthreads();
    }
    int excl = sc[tid] - (h0 + h1);
    if (2 * tid     < NT) bs[2 * tid]     = excl;
    if (2 * tid + 1 < NT) bs[2 * tid + 1] = excl + h0;
    if (tid == 1023) bs[NT] = sc[1023];
    __syncthreads();

    const int stride = SCAT_BLOCKS * 1024;
    const int start  = blockIdx.x * 1024 + tid;
    unsigned ra[SCAT_IT], rb[SCAT_IT], rc[SCAT_IT];
#pragma unroll
    for (int it = 0; it < SCAT_IT; ++it) {
        int i = start + it * stride;
        if (i < n) {
            float2 p = pos[i];
            float I  = inten[i];
            float px = p.x + MARG, py = p.y + MARG;
            int row, col;
            int bin = bin_of(px, py, row, col);
            float dy = py - (float)row, dx = px - (float)col;
            atomicAdd(&lhist[bin], 1);
            ra[it] = ((unsigned)bin << 12) | (unsigned)(((row & 63) << 6) | (col & 63));
            rb[it] = (unsigned)__half_as_ushort(__float2half(dx))
                   | ((unsigned)__half_as_ushort(__float2half(dy)) << 16);
            rc[it] = (unsigned)__half_as_ushort(__float2half(I));
        }
    }
    __syncthreads();
    for (int i = tid; i < NT; i += 1024) {
        int c = lhist[i];
        lbase[i] = (c > 0) ? (bs[i] + atomicAdd(&cursorRel[i], c)) : 0;
        lhist[i] = 0;
    }
    __syncthreads();
#pragma unroll
    for (int it = 0; it < SCAT_IT; ++it) {
        int i = start + it * stride;
        if (i < n) {
            unsigned a = ra[it];
            int bin = (int)(a >> 12);
            int off = atomicAdd(&lhist[bin], 1);
            ushort4 rec;
            rec.x = (unsigned short)(a & 4095u);
            rec.y = (unsigned short)(rb[it] & 0xffffu);
            rec.z = (unsigned short)(rb[it] >> 16);
            rec.w = (unsigned short)rc[it];
            bins[lbase[bin] + off] = rec;
        }
    }
    if (blockIdx.x == 0)
        for (int i = tid; i <= NT; i += 1024) binStart[i] = bs[i];
}

// --- pass 3: per-tile splat via LDS atomics, then coalesced canvas write
__global__ __launch_bounds__(512, 8) void tile_splat_kernel(const ushort4* __restrict__ bins,
                                                            const int* __restrict__ binStart,
                                                            float* __restrict__ canvas) {
    __shared__ float tile[TP * TP];   // 16.9 KB
    const int b  = blockIdx.x;
    const int ti = b / TDIM, tj = b % TDIM;
    for (int i = threadIdx.x; i < TP * TP; i += 512) tile[i] = 0.0f;
    __syncthreads();
    const int s0 = binStart[b], s1 = binStart[b + 1];
    for (int i = s0 + threadIdx.x; i < s1; i += 512) {
        ushort4 r = bins[i];
        int cell = r.x;
        float dx = __half2float(__ushort_as_half(r.y));
        float dy = __half2float(__ushort_as_half(r.z));
        float I  = __half2float(__ushort_as_half(r.w));
        int lr = cell >> 6, lc = cell & 63;
        float omdy = 1.0f - dy, omdx = 1.0f - dx;
        atomicAdd(&tile[lr * TP + lc],           omdy * omdx * I);
        atomicAdd(&tile[(lr + 1) * TP + lc],     dy   * omdx * I);
        atomicAdd(&tile[lr * TP + lc + 1],       omdy * dx   * I);
        atomicAdd(&tile[(lr + 1) * TP + lc + 1], dy   * dx   * I);
    }
    __syncthreads();
    for (int i = threadIdx.x; i < TP * TP; i += 512) {
        int r = i / TP, c = i - r * TP;
        int gr = (ti << TSH) + r, gc = (tj << TSH) + c;
        if (gr < HP && gc < WP) {
            float v = tile[i];
            bool edge = (r == 0) | (c == 0) | (r == TS) | (c == TS);
            if (edge) { if (v != 0.0f) atomicAdd(&canvas[gr * WP + gc], v); }
            else canvas[gr * WP + gc] = v;
        }
    }
}

// --- pass 4: horizontal conv, 4 outputs/thread, aligned float4 LDS window reads.
// Outputs canvas cols [16,2064); taps stay in [0,2080) so no guards anywhere.
__global__ __launch_bounds__(256) void hconv_kernel(const float* __restrict__ canvas,
                                                    float* __restrict__ temp) {
    __shared__ float s[1056];         // input cols x0-16 .. x0+1039
    const int tid = threadIdx.x;
    const int y   = blockIdx.y;
    const int x0  = MARG + (blockIdx.x << 10);    // 16 or 1040
    float wreg[RAD + 1];
    make_weights(wreg);
    const float* rowp = canvas + (size_t)y * WP + (x0 - MARG);  // 16B-aligned
    float4* s4 = (float4*)s;
    const float4* g4 = (const float4*)rowp;
    for (int i = tid; i < 264; i += 256) s4[i] = g4[i];
    __syncthreads();
    float win[36];
#pragma unroll
    for (int j = 0; j < 9; ++j) {
        float4 c = s4[tid + j];
        win[4 * j + 0] = c.x; win[4 * j + 1] = c.y;
        win[4 * j + 2] = c.z; win[4 * j + 3] = c.w;
    }
    float a0 = 0, a1 = 0, a2 = 0, a3 = 0;
#pragma unroll
    for (int u = 0; u < 36; ++u) {
        float v = win[u];
        if (u     <= 32) a0 += v * wreg[(u - 16 < 0) ? 16 - u : u - 16];
        if (u >= 1 && u <= 33) a1 += v * wreg[(u - 17 < 0) ? 17 - u : u - 17];
        if (u >= 2 && u <= 34) a2 += v * wreg[(u - 18 < 0) ? 18 - u : u - 18];
        if (u >= 3)            a3 += v * wreg[(u - 19 < 0) ? 19 - u : u - 19];
    }
    float4 o; o.x = a0; o.y = a1; o.z = a2; o.w = a3;
    *(float4*)&temp[(size_t)y * WP + x0 + (tid << 2)] = o;
}

// --- pass 5: vertical conv + crop, 16 outputs/thread in 4 groups of 4.
// Output row oy needs temp rows oy+MARG-RAD..oy+MARG+RAD = oy..oy+32 (MARG==RAD),
// so block loads temp rows oy0..oy0+95 — always in [0,HP), no guard.
// (Round-6 bug: loaded oy0-RAD+r, dropping the +MARG — 16-row shift, absmax 0.4.)
__global__ __launch_bounds__(256) void vconv_kernel(const float* __restrict__ temp,
                                                    float* __restrict__ out) {
    __shared__ float s[96][64];       // rows oy0 .. oy0+95 (24 KB)
    const int lx = threadIdx.x & 63;
    const int ly = threadIdx.x >> 6;  // 0..3
    const int ox0 = blockIdx.x << 6, oy0 = blockIdx.y << 6;
    const int cx  = ox0 + lx + MARG;
    float wreg[RAD + 1];
    make_weights(wreg);
    for (int r = ly; r < 96; r += 4)
        s[r][lx] = temp[(size_t)(oy0 + r) * WP + cx];
    __syncthreads();
    for (int g = 0; g < 4; ++g) {
        const int yy0 = (ly << 4) + (g << 2);
        float win[36];
#pragma unroll
        for (int u = 0; u < 36; ++u) win[u] = s[yy0 + u][lx];
        float a0 = 0, a1 = 0, a2 = 0, a3 = 0;
#pragma unroll
        for (int u = 0; u < 36; ++u) {
            float v = win[u];
            if (u     <= 32) a0 += v * wreg[(u - 16 < 0) ? 16 - u : u - 16];
            if (u >= 1 && u <= 33) a1 += v * wreg[(u - 17 < 0) ? 17 - u : u - 17];
            if (u >= 2 && u <= 34) a2 += v * wreg[(u - 18 < 0) ? 18 - u : u - 18];
            if (u >= 3)            a3 += v * wreg[(u - 19 < 0) ? 19 - u : u - 19];
        }
        out[(size_t)(oy0 + yy0    ) * WOUT + ox0 + lx] = a0;
        out[(size_t)(oy0 + yy0 + 1) * WOUT + ox0 + lx] = a1;
        out[(size_t)(oy0 + yy0 + 2) * WOUT + ox0 + lx] = a2;
        out[(size_t)(oy0 + yy0 + 3) * WOUT + ox0 + lx] = a3;
    }
}

extern "C" void kernel_launch(void* const* d_in, const int* in_sizes, int n_in,
                              void* d_out, int out_size, void* d_ws, size_t ws_size,
                              hipStream_t stream) {
    const float2* pos   = (const float2*)d_in[0];   // (N,2) as (x,y)
    const float*  inten = (const float*)d_in[1];
    const int n = in_sizes[1];

    float*   canvas   = (float*)d_ws;                       // HP*WP floats
    int*     hist     = (int*)(canvas + (size_t)HP * WP);   // NT
    int*     cursor   = hist + NT;                          // NT
    int*     binStart = cursor + NT;                        // NT+1
    float*   temp     = canvas + (size_t)HP * WP + 4096;    // HP*WP floats
    ushort4* bins     = (ushort4*)temp;                     // n*8 B, aliases temp (read before hconv writes)

    // zero canvas + hist + cursor in one fill (binStart fully written by scatter)
    hipMemsetAsync(canvas, 0, ((size_t)HP * WP + 2 * NT) * sizeof(float), stream);
    hist_kernel<<<HIST_BLOCKS, 256, 0, stream>>>(pos, hist, n);
    scatter_kernel<<<SCAT_BLOCKS, 1024, 0, stream>>>(pos, inten, hist, cursor, binStart, bins, n);
    tile_splat_kernel<<<NT, 512, 0, stream>>>(bins, binStart, canvas);
    hconv_kernel<<<dim3(2, HP), 256, 0, stream>>>(canvas, temp);
    vconv_kernel<<<dim3(WOUT / 64, HOUT / 64), 256, 0, stream>>>(temp, (float*)d_out);
}